// Round 9
// baseline (461.325 us; speedup 1.0000x reference)
//
#include <hip/hip_runtime.h>
#include <hip/hip_fp16.h>
#include <math.h>

#define N_NODES 100000
#define N_EDGES 1600000
#define IN_CH 128
#define HID 64
#define HEADS 2
#define NEG_SLOPE 0.2f

#define NB_SCAN ((N_NODES + 255) / 256)   // 391 scan blocks
#define SHARD_SZ 12500                    // 100000 / 8 XCD shards

static __device__ inline ushort f2h(float f) { return __half_as_ushort(__float2half(f)); }
static __device__ inline float h2f(ushort u) { return __half2float(__ushort_as_half(u)); }
static __device__ inline void h8f(uint4 u, float f[8]) {
    f[0] = h2f((ushort)(u.x & 0xffff)); f[1] = h2f((ushort)(u.x >> 16));
    f[2] = h2f((ushort)(u.y & 0xffff)); f[3] = h2f((ushort)(u.y >> 16));
    f[4] = h2f((ushort)(u.z & 0xffff)); f[5] = h2f((ushort)(u.z >> 16));
    f[6] = h2f((ushort)(u.w & 0xffff)); f[7] = h2f((ushort)(u.w >> 16));
}
static __device__ inline uint pack2(float a, float b) {
    return (uint)f2h(a) | ((uint)f2h(b) << 16);
}

__device__ inline float leaky(float a) { return (a >= 0.0f) ? a : NEG_SLOPE * a; }

// ---------------- CSR build ----------------

__global__ void k_count(const int* __restrict__ dst, int* count) {
    int e = blockIdx.x * 256 + threadIdx.x;
    if (e < N_EDGES) atomicAdd(&count[dst[e]], 1);
}

__global__ void k_scan_a(const int* __restrict__ count, int* __restrict__ incl,
                         int* __restrict__ bsum) {
    __shared__ int sh[256];
    int tid = threadIdx.x;
    int g = blockIdx.x * 256 + tid;
    int v = (g < N_NODES) ? count[g] : 0;
    sh[tid] = v;
    __syncthreads();
    for (int off = 1; off < 256; off <<= 1) {
        int t = (tid >= off) ? sh[tid - off] : 0;
        __syncthreads();
        sh[tid] += t;
        __syncthreads();
    }
    if (g < N_NODES) incl[g] = sh[tid];
    if (tid == 255) bsum[blockIdx.x] = sh[255];
}

__global__ void k_scan_b(const int* __restrict__ bsum, int* __restrict__ boff) {
    __shared__ int sh[512];
    int tid = threadIdx.x;
    int v = (tid < NB_SCAN) ? bsum[tid] : 0;
    sh[tid] = v;
    __syncthreads();
    for (int off = 1; off < 512; off <<= 1) {
        int t = (tid >= off) ? sh[tid - off] : 0;
        __syncthreads();
        sh[tid] += t;
        __syncthreads();
    }
    if (tid < NB_SCAN) boff[tid] = sh[tid] - v;   // exclusive
}

__global__ void k_scan_c(const int* __restrict__ count, const int* __restrict__ incl,
                         const int* __restrict__ boff, int* rowptr, int* cursor) {
    int g = blockIdx.x * 256 + threadIdx.x;
    if (g >= N_NODES) return;
    int excl = incl[g] - count[g] + boff[blockIdx.x];
    rowptr[g] = excl;
    cursor[g] = excl;
    if (g == N_NODES - 1) rowptr[N_NODES] = incl[g] + boff[blockIdx.x];
}

// sharded scatter: one 8B store {src, raw ew} per edge; writes + cursor atomics XCD-local
__global__ void k_scatter(const int* __restrict__ src, const int* __restrict__ dst,
                          const float* __restrict__ ew,
                          int* cursor, int2* __restrict__ ep) {
    int shard = blockIdx.x & 7;
    int e = (blockIdx.x >> 3) * 256 + threadIdx.x;
    if (e >= N_EDGES) return;
    int d = dst[e];
    if (d / SHARD_SZ != shard) return;
    int pos = atomicAdd(&cursor[d], 1);
    ep[pos] = make_int2(src[e], __float_as_int(ew[e]));
}

// deg/dinv from CSR: coalesced sequential reads, no atomics. deg = 1 (self-loop) + sum ew.
__global__ void k_deg_dinv(const int* __restrict__ rowptr, const int2* __restrict__ ep,
                           float* __restrict__ dinv) {
    int n = blockIdx.x * 256 + threadIdx.x;
    if (n >= N_NODES) return;
    int r0 = rowptr[n], r1 = rowptr[n + 1];
    float deg = 1.0f;
    for (int i = r0; i < r1; ++i) deg += __int_as_float(ep[i].y);
    dinv[n] = rsqrtf(deg);
}

// ---------------- dense: register-tiled GEMMs, padded LDS ----------------

// h1 = x @ gcn_w   [N,128]@[128,64] -> fp16.  K staged in two 64-chunks.
__global__ __launch_bounds__(256) void k_gemm1(const float* __restrict__ x,
                                               const float* __restrict__ w,
                                               ushort4* __restrict__ h1h) {
    __shared__ float sxT[64][65];    // [k][r], +1 pad: transpose store <=2-way conflict
    __shared__ float sw[128][64];    // [k][c]
    int t = threadIdx.x;
    int tx = t & 15, ty = t >> 4;
    int row0 = blockIdx.x * 64;
    for (int i = t; i < 128 * 16; i += 256)
        ((float4*)sw)[i] = ((const float4*)w)[i];
    float acc[4][4] = {};
    for (int c = 0; c < 2; ++c) {
        __syncthreads();   // chunk reuse guard (also orders after w staging for c=0)
        for (int i = t; i < 64 * 16; i += 256) {
            int r = i >> 4, kq = i & 15;
            int row = row0 + r;
            float4 v = make_float4(0.f, 0.f, 0.f, 0.f);
            if (row < N_NODES) v = ((const float4*)x)[row * 32 + c * 16 + kq];
            int k = kq * 4;
            sxT[k][r] = v.x; sxT[k + 1][r] = v.y; sxT[k + 2][r] = v.z; sxT[k + 3][r] = v.w;
        }
        __syncthreads();
        #pragma unroll 8
        for (int k = 0; k < 64; ++k) {
            float a0 = sxT[k][ty * 4], a1 = sxT[k][ty * 4 + 1];
            float a2 = sxT[k][ty * 4 + 2], a3 = sxT[k][ty * 4 + 3];
            float4 bb = *(const float4*)&sw[c * 64 + k][tx * 4];
            acc[0][0] += a0 * bb.x; acc[0][1] += a0 * bb.y; acc[0][2] += a0 * bb.z; acc[0][3] += a0 * bb.w;
            acc[1][0] += a1 * bb.x; acc[1][1] += a1 * bb.y; acc[1][2] += a1 * bb.z; acc[1][3] += a1 * bb.w;
            acc[2][0] += a2 * bb.x; acc[2][1] += a2 * bb.y; acc[2][2] += a2 * bb.z; acc[2][3] += a2 * bb.w;
            acc[3][0] += a3 * bb.x; acc[3][1] += a3 * bb.y; acc[3][2] += a3 * bb.z; acc[3][3] += a3 * bb.w;
        }
    }
    #pragma unroll
    for (int i = 0; i < 4; ++i) {
        int row = row0 + ty * 4 + i;
        if (row < N_NODES) {
            ushort4 o;
            o.x = f2h(acc[i][0]); o.y = f2h(acc[i][1]); o.z = f2h(acc[i][2]); o.w = f2h(acc[i][3]);
            h1h[row * 16 + tx] = o;
        }
    }
}

// h2 = agg1(fp16) @ gat_w [N,64]@[64,128] -> fp16; grid = tiles x 2 column halves.
// half == head: fused attention scores ss/sd from fp32 acc in epilogue.
__global__ __launch_bounds__(256) void k_gemm2(const uint4* __restrict__ a16,
                                               const float* __restrict__ w,
                                               const float* __restrict__ att_src,
                                               const float* __restrict__ att_dst,
                                               ushort4* __restrict__ h2h,
                                               float* __restrict__ ss, float* __restrict__ sd) {
    __shared__ float sxT[64][65];    // [k][r] padded
    __shared__ float swh[64][64];    // [k][c] (column half)
    int t = threadIdx.x;
    int tx = t & 15, ty = t >> 4;
    int tile = blockIdx.x >> 1, half = blockIdx.x & 1;
    int row0 = tile * 64;
    for (int i = t; i < 64 * 16; i += 256) {
        int k = i >> 4, cq = i & 15;
        float4 v = ((const float4*)(w + k * 128 + half * 64))[cq];
        ((float4*)&swh[k][cq * 4])[0] = v;
    }
    for (int i = t; i < 64 * 8; i += 256) {   // a tile: 64 rows x 8 uint4 (8 halves each)
        int r = i >> 3, j = i & 7;
        int row = row0 + r;
        float f[8] = {};
        if (row < N_NODES) { uint4 u = a16[row * 8 + j]; h8f(u, f); }
        int k = j * 8;
        #pragma unroll
        for (int m = 0; m < 8; ++m) sxT[k + m][r] = f[m];
    }
    __syncthreads();
    float acc[4][4] = {};
    #pragma unroll 8
    for (int k = 0; k < 64; ++k) {
        float a0 = sxT[k][ty * 4], a1 = sxT[k][ty * 4 + 1];
        float a2 = sxT[k][ty * 4 + 2], a3 = sxT[k][ty * 4 + 3];
        float4 bb = *(const float4*)&swh[k][tx * 4];
        acc[0][0] += a0 * bb.x; acc[0][1] += a0 * bb.y; acc[0][2] += a0 * bb.z; acc[0][3] += a0 * bb.w;
        acc[1][0] += a1 * bb.x; acc[1][1] += a1 * bb.y; acc[1][2] += a1 * bb.z; acc[1][3] += a1 * bb.w;
        acc[2][0] += a2 * bb.x; acc[2][1] += a2 * bb.y; acc[2][2] += a2 * bb.z; acc[2][3] += a2 * bb.w;
        acc[3][0] += a3 * bb.x; acc[3][1] += a3 * bb.y; acc[3][2] += a3 * bb.z; acc[3][3] += a3 * bb.w;
    }
    float as0 = att_src[half * 64 + tx * 4],     as1 = att_src[half * 64 + tx * 4 + 1];
    float as2 = att_src[half * 64 + tx * 4 + 2], as3 = att_src[half * 64 + tx * 4 + 3];
    float ad0 = att_dst[half * 64 + tx * 4],     ad1 = att_dst[half * 64 + tx * 4 + 1];
    float ad2 = att_dst[half * 64 + tx * 4 + 2], ad3 = att_dst[half * 64 + tx * 4 + 3];
    #pragma unroll
    for (int i = 0; i < 4; ++i) {
        int row = row0 + ty * 4 + i;
        float ps = acc[i][0] * as0 + acc[i][1] * as1 + acc[i][2] * as2 + acc[i][3] * as3;
        float pd = acc[i][0] * ad0 + acc[i][1] * ad1 + acc[i][2] * ad2 + acc[i][3] * ad3;
        #pragma unroll
        for (int off = 1; off < 16; off <<= 1) {
            ps += __shfl_xor(ps, off, 64);
            pd += __shfl_xor(pd, off, 64);
        }
        if (row < N_NODES) {
            if (tx == 0) { ss[row * 2 + half] = ps; sd[row * 2 + half] = pd; }
            ushort4 o;
            o.x = f2h(acc[i][0]); o.y = f2h(acc[i][1]); o.z = f2h(acc[i][2]); o.w = f2h(acc[i][3]);
            h2h[row * 32 + half * 16 + tx] = o;
        }
    }
}

// ---------------- segment gather kernels (two-phase, LDS-staged broadcast) ----------

// GCN: wave = node. Phase 1: 64 lanes each prep one edge (64 parallel chains), stage
// {src, weight} in per-wave LDS. Phase 2: 8 groups x 8 lanes gather rows; src/weight
// read from LDS (wave-uniform per group -> broadcast); trip count uniform over wave.
__global__ void k_gcn_csr(const int* __restrict__ rowptr, const int2* __restrict__ ep,
                          const float* __restrict__ dinv,
                          const uint4* __restrict__ h1q, const float* __restrict__ b,
                          uint4* __restrict__ agg1h) {
    __shared__ int   s_src[4][64];
    __shared__ float s_wl[4][64];
    int t = threadIdx.x;
    int w = t >> 6;
    int n = blockIdx.x * 4 + w;
    if (n >= N_NODES) return;
    int lane = t & 63, q = lane >> 3, r = lane & 7;
    int r0 = rowptr[n], r1 = rowptr[n + 1];
    float dn = dinv[n];
    float acc[8] = {};
    if (q == 0) {
        float f[8]; h8f(h1q[n * 8 + r], f);
        #pragma unroll
        for (int j = 0; j < 8; ++j) acc[j] = dn * f[j];
    }
    for (int base = r0; base < r1; base += 64) {
        int m = min(64, r1 - base);
        int sv = 0; float wlv = 0.f;
        if (lane < m) {
            int2 e = ep[base + lane];
            sv = e.x;
            wlv = dinv[sv] * __int_as_float(e.y);
        }
        s_src[w][lane] = sv;     // all 64 lanes store (pad lanes store 0) — uniform
        s_wl[w][lane] = wlv;
        int kmax = (m + 7) >> 3;     // wave-uniform trip count
        for (int k = 0; k < kmax; ++k) {
            int j = q + 8 * k;
            int jj = min(j, m - 1);          // clamp: pad lanes re-read a valid edge
            int s = s_src[w][jj];            // same addr across group -> LDS broadcast
            float wl = (j < m) ? s_wl[w][jj] : 0.f;
            float f[8]; h8f(h1q[s * 8 + r], f);
            #pragma unroll
            for (int c = 0; c < 8; ++c) acc[c] += wl * f[c];
        }
    }
    #pragma unroll
    for (int off = 8; off < 64; off <<= 1) {
        #pragma unroll
        for (int j = 0; j < 8; ++j) acc[j] += __shfl_xor(acc[j], off, 64);
    }
    if (q == 0) {
        float4 b0 = ((const float4*)b)[2 * r], b1 = ((const float4*)b)[2 * r + 1];
        float v0 = fmaxf(acc[0] * dn + b0.x, 0.f), v1 = fmaxf(acc[1] * dn + b0.y, 0.f);
        float v2 = fmaxf(acc[2] * dn + b0.z, 0.f), v3 = fmaxf(acc[3] * dn + b0.w, 0.f);
        float v4 = fmaxf(acc[4] * dn + b1.x, 0.f), v5 = fmaxf(acc[5] * dn + b1.y, 0.f);
        float v6 = fmaxf(acc[6] * dn + b1.z, 0.f), v7 = fmaxf(acc[7] * dn + b1.w, 0.f);
        uint4 o;
        o.x = pack2(v0, v1); o.y = pack2(v2, v3); o.z = pack2(v4, v5); o.w = pack2(v6, v7);
        agg1h[n * 8 + r] = o;
    }
}

// GAT: block=128 -> 1 node; wave = head. Phase 1: 64 lanes each compute one edge's
// exp (64 parallel score chains; den via full-wave butterfly), stage {src, ex} in LDS.
// Phase 2: feature gather, src/ex from LDS broadcast; uniform trip count.
// No max pass: scores are O(+-few), exp cannot overflow fp32; softmax shift-invariant.
__global__ void k_gat_csr(const int* __restrict__ rowptr, const int2* __restrict__ ep,
                          const float* __restrict__ ss, const float* __restrict__ sd,
                          const uint4* __restrict__ h2q, const float* __restrict__ b,
                          float* __restrict__ out) {
    __shared__ int   s_src[2][64];
    __shared__ float s_ex[2][64];
    __shared__ __align__(16) float lds[2][64];
    int n = blockIdx.x;
    int t = threadIdx.x;
    int head = t >> 6, lane = t & 63;
    int q = lane >> 3, r = lane & 7;
    int r0 = rowptr[n], r1 = rowptr[n + 1];
    float sdn = sd[n * 2 + head];
    float exs = __expf(leaky(ss[n * 2 + head] + sdn));
    float den = exs;                       // wave-uniform
    float acc[8] = {};
    if (q == 0) {
        float f[8]; h8f(h2q[n * 16 + head * 8 + r], f);
        #pragma unroll
        for (int j = 0; j < 8; ++j) acc[j] = exs * f[j];
    }
    for (int base = r0; base < r1; base += 64) {
        int m = min(64, r1 - base);
        int sv = 0; float exv = 0.f;
        if (lane < m) {
            sv = ep[base + lane].x;
            exv = __expf(leaky(ss[sv * 2 + head] + sdn));
        }
        s_src[head][lane] = sv;
        s_ex[head][lane] = exv;
        float dsum = exv;                  // chunk denominator (pad lanes = 0)
        #pragma unroll
        for (int off = 1; off < 64; off <<= 1) dsum += __shfl_xor(dsum, off, 64);
        den += dsum;
        int kmax = (m + 7) >> 3;           // wave-uniform trip count
        for (int k = 0; k < kmax; ++k) {
            int j = q + 8 * k;
            int jj = min(j, m - 1);
            int s = s_src[head][jj];
            float ex = (j < m) ? s_ex[head][jj] : 0.f;
            float f[8]; h8f(h2q[s * 16 + head * 8 + r], f);
            #pragma unroll
            for (int c = 0; c < 8; ++c) acc[c] += ex * f[c];
        }
    }
    #pragma unroll
    for (int off = 8; off < 64; off <<= 1) {
        #pragma unroll
        for (int j = 0; j < 8; ++j) acc[j] += __shfl_xor(acc[j], off, 64);
    }
    if (q == 0) {
        float inv = 1.0f / fmaxf(den, 1e-16f);
        *(float4*)&lds[head][r * 8]     = make_float4(acc[0] * inv, acc[1] * inv, acc[2] * inv, acc[3] * inv);
        *(float4*)&lds[head][r * 8 + 4] = make_float4(acc[4] * inv, acc[5] * inv, acc[6] * inv, acc[7] * inv);
    }
    __syncthreads();
    if (t < 64) {
        float v = 0.5f * (lds[0][t] + lds[1][t]) + b[t];
        out[n * 64 + t] = fmaxf(v, 0.0f);
    }
}

// ---------------- launch ----------------
extern "C" void kernel_launch(void* const* d_in, const int* in_sizes, int n_in,
                              void* d_out, int out_size, void* d_ws, size_t ws_size,
                              hipStream_t stream) {
    const float* x       = (const float*)d_in[0];
    const int*   eidx    = (const int*)d_in[1];
    const float* ew      = (const float*)d_in[2];
    const float* gcn_w   = (const float*)d_in[3];
    const float* gcn_b   = (const float*)d_in[4];
    const float* gat_w   = (const float*)d_in[5];
    const float* att_src = (const float*)d_in[6];
    const float* att_dst = (const float*)d_in[7];
    const float* gat_b   = (const float*)d_in[8];
    float* out = (float*)d_out;

    const int* src = eidx;            // edge_index[0]
    const int* dst = eidx + N_EDGES;  // edge_index[1]

    // workspace layout (16B-aligned blocks first)
    char* p = (char*)d_ws;
    ushort* agg1h = (ushort*)p; p += sizeof(ushort) * (size_t)N_NODES * 64;   // fp16
    ushort* h1h   = (ushort*)p; p += sizeof(ushort) * (size_t)N_NODES * 64;   // fp16
    ushort* h2h   = (ushort*)p; p += sizeof(ushort) * (size_t)N_NODES * 128;  // fp16
    int2*  ep     = (int2*)p;   p += sizeof(int2) * (size_t)N_EDGES;          // {src, ew}
    int*   count  = (int*)p;    p += sizeof(int) * N_NODES;
    float* dinv   = (float*)p;  p += sizeof(float) * N_NODES;
    int*   incl   = (int*)p;    p += sizeof(int) * N_NODES;
    int*   rowptr = (int*)p;    p += sizeof(int) * (N_NODES + 1);
    int*   cursor = (int*)p;    p += sizeof(int) * N_NODES;
    float* ss     = (float*)p;  p += sizeof(float) * N_NODES * 2;
    float* sd     = (float*)p;  p += sizeof(float) * N_NODES * 2;
    int*   bsum   = (int*)p;    p += sizeof(int) * NB_SCAN;
    int*   boff   = (int*)p;    p += sizeof(int) * NB_SCAN;

    const int T = 256;
    const int NBe  = (N_EDGES + T - 1) / T;
    const int NBe8 = 8 * NBe;   // sharded scatter grid

    // CSR build
    hipMemsetAsync(count, 0, sizeof(int) * N_NODES, stream);
    k_count<<<NBe, T, 0, stream>>>(dst, count);
    k_scan_a<<<NB_SCAN, T, 0, stream>>>(count, incl, bsum);
    k_scan_b<<<1, 512, 0, stream>>>(bsum, boff);
    k_scan_c<<<NB_SCAN, T, 0, stream>>>(count, incl, boff, rowptr, cursor);
    k_scatter<<<NBe8, T, 0, stream>>>(src, dst, ew, cursor, ep);
    k_deg_dinv<<<NB_SCAN, T, 0, stream>>>(rowptr, ep, dinv);

    // layer 1: GCN
    k_gemm1<<<(N_NODES + 63) / 64, T, 0, stream>>>(x, gcn_w, (ushort4*)h1h);
    k_gcn_csr<<<(N_NODES + 3) / 4, T, 0, stream>>>(rowptr, ep, dinv, (const uint4*)h1h, gcn_b, (uint4*)agg1h);

    // layer 2: GAT (scores fused into gemm2 epilogue)
    k_gemm2<<<((N_NODES + 63) / 64) * 2, T, 0, stream>>>((const uint4*)agg1h, gat_w, att_src, att_dst, (ushort4*)h2h, ss, sd);
    k_gat_csr<<<N_NODES, 128, 0, stream>>>(rowptr, ep, ss, sd, (const uint4*)h2h, gat_b, out);
}

// Round 10
// 444.224 us; speedup vs baseline: 1.0385x; 1.0385x over previous
//
#include <hip/hip_runtime.h>
#include <hip/hip_fp16.h>
#include <math.h>

#define N_NODES 100000
#define N_EDGES 1600000
#define IN_CH 128
#define HID 64
#define HEADS 2
#define NEG_SLOPE 0.2f

#define NB_SCAN ((N_NODES + 255) / 256)   // 391 scan blocks
#define SHARD_SZ 12500                    // 100000 / 8 XCD shards

static __device__ inline ushort f2h(float f) { return __half_as_ushort(__float2half(f)); }
static __device__ inline float h2f(ushort u) { return __half2float(__ushort_as_half(u)); }
static __device__ inline void h8f(uint4 u, float f[8]) {
    f[0] = h2f((ushort)(u.x & 0xffff)); f[1] = h2f((ushort)(u.x >> 16));
    f[2] = h2f((ushort)(u.y & 0xffff)); f[3] = h2f((ushort)(u.y >> 16));
    f[4] = h2f((ushort)(u.z & 0xffff)); f[5] = h2f((ushort)(u.z >> 16));
    f[6] = h2f((ushort)(u.w & 0xffff)); f[7] = h2f((ushort)(u.w >> 16));
}
static __device__ inline uint pack2(float a, float b) {
    return (uint)f2h(a) | ((uint)f2h(b) << 16);
}

__device__ inline float leaky(float a) { return (a >= 0.0f) ? a : NEG_SLOPE * a; }

// ---------------- CSR build ----------------

__global__ void k_count(const int* __restrict__ dst, int* count) {
    int e = blockIdx.x * 256 + threadIdx.x;
    if (e < N_EDGES) atomicAdd(&count[dst[e]], 1);
}

__global__ void k_scan_a(const int* __restrict__ count, int* __restrict__ incl,
                         int* __restrict__ bsum) {
    __shared__ int sh[256];
    int tid = threadIdx.x;
    int g = blockIdx.x * 256 + tid;
    int v = (g < N_NODES) ? count[g] : 0;
    sh[tid] = v;
    __syncthreads();
    for (int off = 1; off < 256; off <<= 1) {
        int t = (tid >= off) ? sh[tid - off] : 0;
        __syncthreads();
        sh[tid] += t;
        __syncthreads();
    }
    if (g < N_NODES) incl[g] = sh[tid];
    if (tid == 255) bsum[blockIdx.x] = sh[255];
}

__global__ void k_scan_b(const int* __restrict__ bsum, int* __restrict__ boff) {
    __shared__ int sh[512];
    int tid = threadIdx.x;
    int v = (tid < NB_SCAN) ? bsum[tid] : 0;
    sh[tid] = v;
    __syncthreads();
    for (int off = 1; off < 512; off <<= 1) {
        int t = (tid >= off) ? sh[tid - off] : 0;
        __syncthreads();
        sh[tid] += t;
        __syncthreads();
    }
    if (tid < NB_SCAN) boff[tid] = sh[tid] - v;   // exclusive
}

__global__ void k_scan_c(const int* __restrict__ count, const int* __restrict__ incl,
                         const int* __restrict__ boff, int* rowptr, int* cursor) {
    int g = blockIdx.x * 256 + threadIdx.x;
    if (g >= N_NODES) return;
    int excl = incl[g] - count[g] + boff[blockIdx.x];
    rowptr[g] = excl;
    cursor[g] = excl;
    if (g == N_NODES - 1) rowptr[N_NODES] = incl[g] + boff[blockIdx.x];
}

// sharded scatter: one 8B store {src, raw ew} per edge; writes + cursor atomics XCD-local
__global__ void k_scatter(const int* __restrict__ src, const int* __restrict__ dst,
                          const float* __restrict__ ew,
                          int* cursor, int2* __restrict__ ep) {
    int shard = blockIdx.x & 7;
    int e = (blockIdx.x >> 3) * 256 + threadIdx.x;
    if (e >= N_EDGES) return;
    int d = dst[e];
    if (d / SHARD_SZ != shard) return;
    int pos = atomicAdd(&cursor[d], 1);
    ep[pos] = make_int2(src[e], __float_as_int(ew[e]));
}

// deg/dinv from CSR: coalesced sequential reads, no atomics. deg = 1 (self-loop) + sum ew.
__global__ void k_deg_dinv(const int* __restrict__ rowptr, const int2* __restrict__ ep,
                           float* __restrict__ dinv) {
    int n = blockIdx.x * 256 + threadIdx.x;
    if (n >= N_NODES) return;
    int r0 = rowptr[n], r1 = rowptr[n + 1];
    float deg = 1.0f;
    for (int i = r0; i < r1; ++i) deg += __int_as_float(ep[i].y);
    dinv[n] = rsqrtf(deg);
}

// ---------------- dense: register-tiled GEMMs, padded LDS ----------------

// h1 = x @ gcn_w   [N,128]@[128,64] -> fp16.  K staged in two 64-chunks.
__global__ __launch_bounds__(256) void k_gemm1(const float* __restrict__ x,
                                               const float* __restrict__ w,
                                               ushort4* __restrict__ h1h) {
    __shared__ float sxT[64][65];    // [k][r], +1 pad: transpose store <=2-way conflict
    __shared__ float sw[128][64];    // [k][c]
    int t = threadIdx.x;
    int tx = t & 15, ty = t >> 4;
    int row0 = blockIdx.x * 64;
    for (int i = t; i < 128 * 16; i += 256)
        ((float4*)sw)[i] = ((const float4*)w)[i];
    float acc[4][4] = {};
    for (int c = 0; c < 2; ++c) {
        __syncthreads();   // chunk reuse guard (also orders after w staging for c=0)
        for (int i = t; i < 64 * 16; i += 256) {
            int r = i >> 4, kq = i & 15;
            int row = row0 + r;
            float4 v = make_float4(0.f, 0.f, 0.f, 0.f);
            if (row < N_NODES) v = ((const float4*)x)[row * 32 + c * 16 + kq];
            int k = kq * 4;
            sxT[k][r] = v.x; sxT[k + 1][r] = v.y; sxT[k + 2][r] = v.z; sxT[k + 3][r] = v.w;
        }
        __syncthreads();
        #pragma unroll 8
        for (int k = 0; k < 64; ++k) {
            float a0 = sxT[k][ty * 4], a1 = sxT[k][ty * 4 + 1];
            float a2 = sxT[k][ty * 4 + 2], a3 = sxT[k][ty * 4 + 3];
            float4 bb = *(const float4*)&sw[c * 64 + k][tx * 4];
            acc[0][0] += a0 * bb.x; acc[0][1] += a0 * bb.y; acc[0][2] += a0 * bb.z; acc[0][3] += a0 * bb.w;
            acc[1][0] += a1 * bb.x; acc[1][1] += a1 * bb.y; acc[1][2] += a1 * bb.z; acc[1][3] += a1 * bb.w;
            acc[2][0] += a2 * bb.x; acc[2][1] += a2 * bb.y; acc[2][2] += a2 * bb.z; acc[2][3] += a2 * bb.w;
            acc[3][0] += a3 * bb.x; acc[3][1] += a3 * bb.y; acc[3][2] += a3 * bb.z; acc[3][3] += a3 * bb.w;
        }
    }
    #pragma unroll
    for (int i = 0; i < 4; ++i) {
        int row = row0 + ty * 4 + i;
        if (row < N_NODES) {
            ushort4 o;
            o.x = f2h(acc[i][0]); o.y = f2h(acc[i][1]); o.z = f2h(acc[i][2]); o.w = f2h(acc[i][3]);
            h1h[row * 16 + tx] = o;
        }
    }
}

// h2 = agg1(fp16) @ gat_w [N,64]@[64,128] -> fp16; grid = tiles x 2 column halves.
// half == head: fused attention scores ss/sd from fp32 acc in epilogue.
__global__ __launch_bounds__(256) void k_gemm2(const uint4* __restrict__ a16,
                                               const float* __restrict__ w,
                                               const float* __restrict__ att_src,
                                               const float* __restrict__ att_dst,
                                               ushort4* __restrict__ h2h,
                                               float* __restrict__ ss, float* __restrict__ sd) {
    __shared__ float sxT[64][65];    // [k][r] padded
    __shared__ float swh[64][64];    // [k][c] (column half)
    int t = threadIdx.x;
    int tx = t & 15, ty = t >> 4;
    int tile = blockIdx.x >> 1, half = blockIdx.x & 1;
    int row0 = tile * 64;
    for (int i = t; i < 64 * 16; i += 256) {
        int k = i >> 4, cq = i & 15;
        float4 v = ((const float4*)(w + k * 128 + half * 64))[cq];
        ((float4*)&swh[k][cq * 4])[0] = v;
    }
    for (int i = t; i < 64 * 8; i += 256) {   // a tile: 64 rows x 8 uint4 (8 halves each)
        int r = i >> 3, j = i & 7;
        int row = row0 + r;
        float f[8] = {};
        if (row < N_NODES) { uint4 u = a16[row * 8 + j]; h8f(u, f); }
        int k = j * 8;
        #pragma unroll
        for (int m = 0; m < 8; ++m) sxT[k + m][r] = f[m];
    }
    __syncthreads();
    float acc[4][4] = {};
    #pragma unroll 8
    for (int k = 0; k < 64; ++k) {
        float a0 = sxT[k][ty * 4], a1 = sxT[k][ty * 4 + 1];
        float a2 = sxT[k][ty * 4 + 2], a3 = sxT[k][ty * 4 + 3];
        float4 bb = *(const float4*)&swh[k][tx * 4];
        acc[0][0] += a0 * bb.x; acc[0][1] += a0 * bb.y; acc[0][2] += a0 * bb.z; acc[0][3] += a0 * bb.w;
        acc[1][0] += a1 * bb.x; acc[1][1] += a1 * bb.y; acc[1][2] += a1 * bb.z; acc[1][3] += a1 * bb.w;
        acc[2][0] += a2 * bb.x; acc[2][1] += a2 * bb.y; acc[2][2] += a2 * bb.z; acc[2][3] += a2 * bb.w;
        acc[3][0] += a3 * bb.x; acc[3][1] += a3 * bb.y; acc[3][2] += a3 * bb.z; acc[3][3] += a3 * bb.w;
    }
    float as0 = att_src[half * 64 + tx * 4],     as1 = att_src[half * 64 + tx * 4 + 1];
    float as2 = att_src[half * 64 + tx * 4 + 2], as3 = att_src[half * 64 + tx * 4 + 3];
    float ad0 = att_dst[half * 64 + tx * 4],     ad1 = att_dst[half * 64 + tx * 4 + 1];
    float ad2 = att_dst[half * 64 + tx * 4 + 2], ad3 = att_dst[half * 64 + tx * 4 + 3];
    #pragma unroll
    for (int i = 0; i < 4; ++i) {
        int row = row0 + ty * 4 + i;
        float ps = acc[i][0] * as0 + acc[i][1] * as1 + acc[i][2] * as2 + acc[i][3] * as3;
        float pd = acc[i][0] * ad0 + acc[i][1] * ad1 + acc[i][2] * ad2 + acc[i][3] * ad3;
        #pragma unroll
        for (int off = 1; off < 16; off <<= 1) {
            ps += __shfl_xor(ps, off, 64);
            pd += __shfl_xor(pd, off, 64);
        }
        if (row < N_NODES) {
            if (tx == 0) { ss[row * 2 + half] = ps; sd[row * 2 + half] = pd; }
            ushort4 o;
            o.x = f2h(acc[i][0]); o.y = f2h(acc[i][1]); o.z = f2h(acc[i][2]); o.w = f2h(acc[i][3]);
            h2h[row * 32 + half * 16 + tx] = o;
        }
    }
}

// ---------------- segment gather kernels ----------------

// GCN (R6 structure): wave = node; lanes = 8 edge-groups x 8 (8 fp16 ch via uint4).
// norm on the fly: dinv[d] * sum(dinv[s]*ew * h1[s])  (+ self dinv[d]^2 h1[d]).
__global__ void k_gcn_csr(const int* __restrict__ rowptr, const int2* __restrict__ ep,
                          const float* __restrict__ dinv,
                          const uint4* __restrict__ h1q, const float* __restrict__ b,
                          uint4* __restrict__ agg1h) {
    int t = threadIdx.x;
    int n = blockIdx.x * 4 + (t >> 6);
    if (n >= N_NODES) return;
    int lane = t & 63, q = lane >> 3, r = lane & 7;
    int r0 = rowptr[n], r1 = rowptr[n + 1];
    float dn = dinv[n];
    float acc[8] = {};
    if (q == 0) {
        float f[8]; h8f(h1q[n * 8 + r], f);
        #pragma unroll
        for (int j = 0; j < 8; ++j) acc[j] = dn * f[j];
    }
    for (int i = r0 + q; i < r1; i += 8) {
        int2 e = ep[i];
        float wl = dinv[e.x] * __int_as_float(e.y);
        float f[8]; h8f(h1q[e.x * 8 + r], f);
        #pragma unroll
        for (int j = 0; j < 8; ++j) acc[j] += wl * f[j];
    }
    #pragma unroll
    for (int off = 8; off < 64; off <<= 1) {
        #pragma unroll
        for (int j = 0; j < 8; ++j) acc[j] += __shfl_xor(acc[j], off, 64);
    }
    if (q == 0) {
        float4 b0 = ((const float4*)b)[2 * r], b1 = ((const float4*)b)[2 * r + 1];
        float v0 = fmaxf(acc[0] * dn + b0.x, 0.f), v1 = fmaxf(acc[1] * dn + b0.y, 0.f);
        float v2 = fmaxf(acc[2] * dn + b0.z, 0.f), v3 = fmaxf(acc[3] * dn + b0.w, 0.f);
        float v4 = fmaxf(acc[4] * dn + b1.x, 0.f), v5 = fmaxf(acc[5] * dn + b1.y, 0.f);
        float v6 = fmaxf(acc[6] * dn + b1.z, 0.f), v7 = fmaxf(acc[7] * dn + b1.w, 0.f);
        uint4 o;
        o.x = pack2(v0, v1); o.y = pack2(v2, v3); o.z = pack2(v4, v5); o.w = pack2(v6, v7);
        agg1h[n * 8 + r] = o;
    }
}

// GAT: ONE wave = one node, BOTH heads. 4 edge-groups x 16 lanes; each group loads the
// full 256B both-head row (contiguous, lanes' ep addresses consecutive across groups).
// head = (lane&15)>>3. Head-mean via shfl_xor(8) — no LDS, no barrier. All cross-lane
// ops are full-wave butterflies in uniformly-active code.
// No max pass: scores are O(+-few), exp cannot overflow fp32; softmax shift-invariant.
__global__ void k_gat_csr(const int* __restrict__ rowptr, const int2* __restrict__ ep,
                          const float* __restrict__ ss, const float* __restrict__ sd,
                          const uint4* __restrict__ h2q, const float* __restrict__ b,
                          float* __restrict__ out) {
    int t = threadIdx.x;
    int n = blockIdx.x * 4 + (t >> 6);
    if (n >= N_NODES) return;
    int lane = t & 63;
    int g = lane >> 4;            // edge group 0..3
    int t16 = lane & 15;          // uint4 slot in the 256B row
    int head = t16 >> 3;          // 0: ch 0..63 of head0, 1: head1
    int r = t16 & 7;              // channel-octet index within head
    int r0 = rowptr[n], r1 = rowptr[n + 1];
    float sdn = sd[n * 2 + head];
    float den = 0.f;
    float acc[8] = {};
    if (g == 0) {                 // self-loop term (counted once per head via butterfly)
        float exs = __expf(leaky(ss[n * 2 + head] + sdn));
        den = exs;
        float f[8]; h8f(h2q[n * 16 + t16], f);
        #pragma unroll
        for (int j = 0; j < 8; ++j) acc[j] = exs * f[j];
    }
    for (int i = r0 + g; i < r1; i += 4) {
        int s = ep[i].x;
        float ex = __expf(leaky(ss[s * 2 + head] + sdn));
        den += ex;
        float f[8]; h8f(h2q[s * 16 + t16], f);
        #pragma unroll
        for (int j = 0; j < 8; ++j) acc[j] += ex * f[j];
    }
    // reduce across the 4 edge-groups (preserves head: offsets 16,32 keep lane&15)
    #pragma unroll
    for (int off = 16; off < 64; off <<= 1) {
        #pragma unroll
        for (int j = 0; j < 8; ++j) acc[j] += __shfl_xor(acc[j], off, 64);
        den += __shfl_xor(den, off, 64);
    }
    float inv = 1.0f / fmaxf(den, 1e-16f);
    #pragma unroll
    for (int j = 0; j < 8; ++j) acc[j] *= inv;
    // mean over heads: partner lane differs only in bit 3
    float o[8];
    #pragma unroll
    for (int j = 0; j < 8; ++j) o[j] = 0.5f * (acc[j] + __shfl_xor(acc[j], 8, 64));
    if (g == 0 && head == 0) {    // 8 lanes x 8 channels = 64 outputs
        float4 b0 = ((const float4*)b)[2 * r], b1 = ((const float4*)b)[2 * r + 1];
        float4* op = (float4*)(out + n * 64 + r * 8);
        op[0] = make_float4(fmaxf(o[0] + b0.x, 0.f), fmaxf(o[1] + b0.y, 0.f),
                            fmaxf(o[2] + b0.z, 0.f), fmaxf(o[3] + b0.w, 0.f));
        op[1] = make_float4(fmaxf(o[4] + b1.x, 0.f), fmaxf(o[5] + b1.y, 0.f),
                            fmaxf(o[6] + b1.z, 0.f), fmaxf(o[7] + b1.w, 0.f));
    }
}

// ---------------- launch ----------------
extern "C" void kernel_launch(void* const* d_in, const int* in_sizes, int n_in,
                              void* d_out, int out_size, void* d_ws, size_t ws_size,
                              hipStream_t stream) {
    const float* x       = (const float*)d_in[0];
    const int*   eidx    = (const int*)d_in[1];
    const float* ew      = (const float*)d_in[2];
    const float* gcn_w   = (const float*)d_in[3];
    const float* gcn_b   = (const float*)d_in[4];
    const float* gat_w   = (const float*)d_in[5];
    const float* att_src = (const float*)d_in[6];
    const float* att_dst = (const float*)d_in[7];
    const float* gat_b   = (const float*)d_in[8];
    float* out = (float*)d_out;

    const int* src = eidx;            // edge_index[0]
    const int* dst = eidx + N_EDGES;  // edge_index[1]

    // workspace layout (16B-aligned blocks first)
    char* p = (char*)d_ws;
    ushort* agg1h = (ushort*)p; p += sizeof(ushort) * (size_t)N_NODES * 64;   // fp16
    ushort* h1h   = (ushort*)p; p += sizeof(ushort) * (size_t)N_NODES * 64;   // fp16
    ushort* h2h   = (ushort*)p; p += sizeof(ushort) * (size_t)N_NODES * 128;  // fp16
    int2*  ep     = (int2*)p;   p += sizeof(int2) * (size_t)N_EDGES;          // {src, ew}
    int*   count  = (int*)p;    p += sizeof(int) * N_NODES;
    float* dinv   = (float*)p;  p += sizeof(float) * N_NODES;
    int*   incl   = (int*)p;    p += sizeof(int) * N_NODES;
    int*   rowptr = (int*)p;    p += sizeof(int) * (N_NODES + 1);
    int*   cursor = (int*)p;    p += sizeof(int) * N_NODES;
    float* ss     = (float*)p;  p += sizeof(float) * N_NODES * 2;
    float* sd     = (float*)p;  p += sizeof(float) * N_NODES * 2;
    int*   bsum   = (int*)p;    p += sizeof(int) * NB_SCAN;
    int*   boff   = (int*)p;    p += sizeof(int) * NB_SCAN;

    const int T = 256;
    const int NBe  = (N_EDGES + T - 1) / T;
    const int NBe8 = 8 * NBe;   // sharded scatter grid

    // CSR build
    hipMemsetAsync(count, 0, sizeof(int) * N_NODES, stream);
    k_count<<<NBe, T, 0, stream>>>(dst, count);
    k_scan_a<<<NB_SCAN, T, 0, stream>>>(count, incl, bsum);
    k_scan_b<<<1, 512, 0, stream>>>(bsum, boff);
    k_scan_c<<<NB_SCAN, T, 0, stream>>>(count, incl, boff, rowptr, cursor);
    k_scatter<<<NBe8, T, 0, stream>>>(src, dst, ew, cursor, ep);
    k_deg_dinv<<<NB_SCAN, T, 0, stream>>>(rowptr, ep, dinv);

    // layer 1: GCN
    k_gemm1<<<(N_NODES + 63) / 64, T, 0, stream>>>(x, gcn_w, (ushort4*)h1h);
    k_gcn_csr<<<(N_NODES + 3) / 4, T, 0, stream>>>(rowptr, ep, dinv, (const uint4*)h1h, gcn_b, (uint4*)agg1h);

    // layer 2: GAT (scores fused into gemm2 epilogue)
    k_gemm2<<<((N_NODES + 63) / 64) * 2, T, 0, stream>>>((const uint4*)agg1h, gat_w, att_src, att_dst, (ushort4*)h2h, ss, sd);
    k_gat_csr<<<(N_NODES + 3) / 4, T, 0, stream>>>(rowptr, ep, ss, sd, (const uint4*)h2h, gat_b, out);
}